// Round 1
// baseline (634.498 us; speedup 1.0000x reference)
//
#include <hip/hip_runtime.h>
#include <math.h>

#define NN 4096
#define DD 512
#define ELL 128

typedef unsigned long long u64;

// ---------------- build ELL (compact column list per row, ordered) -----------
__global__ __launch_bounds__(256) void k_build_ell(const float* __restrict__ adj,
                                                   int* __restrict__ cols,
                                                   int* __restrict__ cnt) {
  const int wv = threadIdx.x >> 6;
  const int lane = threadIdx.x & 63;
  const int r = blockIdx.x * 4 + wv;
  const float* row = adj + (size_t)r * NN;
  int* rc = cols + (size_t)r * ELL;
  int base = 0;
  for (int c0 = 0; c0 < NN; c0 += 64) {
    float v = row[c0 + lane];
    u64 m = __ballot(v > 0.f);
    if (v > 0.f) {
      int idx = base + __popcll(m & ((1ull << lane) - 1ull));
      if (idx < ELL) rc[idx] = c0 + lane;
    }
    base += __popcll(m);
  }
  if (lane == 0) cnt[r] = base < ELL ? base : ELL;
}

// ---------------- dense f32 GEMM: C_m = A @ W_m + bscale(row) * b_m ----------
// A: [4096 x 512] row-major, W: [512 x 512], C: [4096 x 512].
// Up to 3 weight matrices batched along grid.y for full-GPU utilization.
struct GemmP {
  const float* A;
  const float* W0; const float* W1; const float* W2;
  const float* b0; const float* b1; const float* b2;
  float* C0; float* C1; float* C2;
  const int* bscale;   // per-row bias multiplier (degree); nullptr -> 1.0
};

__global__ __launch_bounds__(256) void k_gemm(GemmP p) {
  __shared__ __align__(16) float As[16][132];  // [k][m], padded
  __shared__ __align__(16) float Bs[16][128];  // [k][n]
  const int tid = threadIdx.x;
  const int tx = tid & 15, ty = tid >> 4;
  const int m0 = blockIdx.x * 128;
  const int bn = blockIdx.y;
  const int mat = bn >> 2;
  const int n0 = (bn & 3) * 128;
  const float* W    = (mat == 0) ? p.W0 : (mat == 1 ? p.W1 : p.W2);
  const float* bias = (mat == 0) ? p.b0 : (mat == 1 ? p.b1 : p.b2);
  float* C          = (mat == 0) ? p.C0 : (mat == 1 ? p.C1 : p.C2);
  const float* A = p.A;

  float acc[8][8];
#pragma unroll
  for (int i = 0; i < 8; i++)
#pragma unroll
    for (int j = 0; j < 8; j++) acc[i][j] = 0.f;

  for (int k0 = 0; k0 < DD; k0 += 16) {
#pragma unroll
    for (int q = 0; q < 2; q++) {           // A tile 128x16, transposed store
      int idx = tid + 256 * q;
      int row = idx >> 2;
      int kk = (idx & 3) << 2;
      float4 v = *reinterpret_cast<const float4*>(A + (size_t)(m0 + row) * DD + k0 + kk);
      As[kk + 0][row] = v.x;
      As[kk + 1][row] = v.y;
      As[kk + 2][row] = v.z;
      As[kk + 3][row] = v.w;
    }
#pragma unroll
    for (int q = 0; q < 2; q++) {           // W tile 16x128
      int idx = tid + 256 * q;
      int kk = idx >> 5;
      int col = (idx & 31) << 2;
      *reinterpret_cast<float4*>(&Bs[kk][col]) =
          *reinterpret_cast<const float4*>(W + (size_t)(k0 + kk) * DD + n0 + col);
    }
    __syncthreads();
#pragma unroll
    for (int kk = 0; kk < 16; kk++) {
      float4 a0 = *reinterpret_cast<const float4*>(&As[kk][ty * 8]);
      float4 a1 = *reinterpret_cast<const float4*>(&As[kk][ty * 8 + 4]);
      float4 b0 = *reinterpret_cast<const float4*>(&Bs[kk][tx * 8]);
      float4 b1 = *reinterpret_cast<const float4*>(&Bs[kk][tx * 8 + 4]);
      float a[8] = {a0.x, a0.y, a0.z, a0.w, a1.x, a1.y, a1.z, a1.w};
      float b[8] = {b0.x, b0.y, b0.z, b0.w, b1.x, b1.y, b1.z, b1.w};
#pragma unroll
      for (int i = 0; i < 8; i++)
#pragma unroll
        for (int j = 0; j < 8; j++) acc[i][j] = fmaf(a[i], b[j], acc[i][j]);
    }
    __syncthreads();
  }

#pragma unroll
  for (int i = 0; i < 8; i++) {
    int m = m0 + ty * 8 + i;
    float bs = p.bscale ? (float)p.bscale[m] : 1.0f;
    float4 o0, o1;
    o0.x = acc[i][0] + bs * bias[n0 + tx * 8 + 0];
    o0.y = acc[i][1] + bs * bias[n0 + tx * 8 + 1];
    o0.z = acc[i][2] + bs * bias[n0 + tx * 8 + 2];
    o0.w = acc[i][3] + bs * bias[n0 + tx * 8 + 3];
    o1.x = acc[i][4] + bs * bias[n0 + tx * 8 + 4];
    o1.y = acc[i][5] + bs * bias[n0 + tx * 8 + 5];
    o1.z = acc[i][6] + bs * bias[n0 + tx * 8 + 6];
    o1.w = acc[i][7] + bs * bias[n0 + tx * 8 + 7];
    *reinterpret_cast<float4*>(C + (size_t)m * DD + n0 + tx * 8) = o0;
    *reinterpret_cast<float4*>(C + (size_t)m * DD + n0 + tx * 8 + 4) = o1;
  }
}

// ---------------- SpMM: C[r] = sum_k vals[r,k] * B[cols[r,k]]  ---------------
__global__ __launch_bounds__(256) void k_spmm(const int* __restrict__ cols,
                                              const int* __restrict__ cnts,
                                              const float* __restrict__ vals,
                                              const float* __restrict__ B,
                                              float* __restrict__ C) {
  const int r = blockIdx.x;
  const int t = threadIdx.x;
  __shared__ int scol[ELL];
  __shared__ float sval[ELL];
  const int cnt = cnts[r];
  if (t < ELL) {
    scol[t] = (t < cnt) ? cols[(size_t)r * ELL + t] : 0;
    sval[t] = (vals && t < cnt) ? vals[(size_t)r * ELL + t] : 1.0f;
  }
  __syncthreads();
  float a0 = 0.f, a1 = 0.f;
#pragma unroll 4
  for (int k = 0; k < cnt; k++) {
    const float* Bj = B + (size_t)scol[k] * DD;
    float v = sval[k];
    a0 = fmaf(v, Bj[t], a0);
    a1 = fmaf(v, Bj[t + 256], a1);
  }
  C[(size_t)r * DD + t] = a0;
  C[(size_t)r * DD + t + 256] = a1;
}

// ------------- SDDMM (masked QK^T) + row softmax (+ dense scatter) -----------
__global__ __launch_bounds__(256) void k_sddmm_softmax(const int* __restrict__ cols,
                                                       const int* __restrict__ cnts,
                                                       const float* __restrict__ Q,
                                                       const float* __restrict__ K,
                                                       float* __restrict__ attval,
                                                       float* __restrict__ dense) {
  const int r = blockIdx.x;
  const int t = threadIdx.x;
  const int lane = t & 63, wv = t >> 6;
  const int cnt = cnts[r];
  __shared__ int scol[ELL];
  __shared__ float ssc[ELL];
  if (t < ELL) scol[t] = (t < cnt) ? cols[(size_t)r * ELL + t] : 0;
  __syncthreads();
  const float* Qr = Q + (size_t)r * DD + lane * 8;
  float4 q0 = *reinterpret_cast<const float4*>(Qr);
  float4 q1 = *reinterpret_cast<const float4*>(Qr + 4);
  for (int k = wv; k < cnt; k += 4) {
    const float* Kj = K + (size_t)scol[k] * DD + lane * 8;
    float4 k0 = *reinterpret_cast<const float4*>(Kj);
    float4 k1 = *reinterpret_cast<const float4*>(Kj + 4);
    float s = q0.x * k0.x + q0.y * k0.y + q0.z * k0.z + q0.w * k0.w +
              q1.x * k1.x + q1.y * k1.y + q1.z * k1.z + q1.w * k1.w;
#pragma unroll
    for (int off = 32; off > 0; off >>= 1) s += __shfl_xor(s, off);
    if (lane == 0) ssc[k] = s;
  }
  __syncthreads();
  if (wv == 0) {
    float v0 = (lane < cnt) ? ssc[lane] : -INFINITY;
    float v1 = (lane + 64 < cnt) ? ssc[lane + 64] : -INFINITY;
    float mx = fmaxf(v0, v1);
#pragma unroll
    for (int off = 32; off > 0; off >>= 1) mx = fmaxf(mx, __shfl_xor(mx, off));
    float e0 = (lane < cnt) ? expf(v0 - mx) : 0.f;
    float e1 = (lane + 64 < cnt) ? expf(v1 - mx) : 0.f;
    float sm = e0 + e1;
#pragma unroll
    for (int off = 32; off > 0; off >>= 1) sm += __shfl_xor(sm, off);
    float inv = 1.f / sm;
    if (lane < cnt) ssc[lane] = e0 * inv;
    if (lane + 64 < cnt) ssc[lane + 64] = e1 * inv;
  }
  __syncthreads();
  if (t < cnt) {
    float v = ssc[t];
    attval[(size_t)r * ELL + t] = v;
    if (dense) dense[(size_t)r * NN + scol[t]] = v;
  }
}

// -------- fused: row-normalize 3 segments + mask + relu + classifier + lsm ---
__global__ __launch_bounds__(256) void k_norm_cls(const float* __restrict__ T0,
                                                  const float* __restrict__ T1,
                                                  const float* __restrict__ T2,
                                                  const float* __restrict__ hop,
                                                  const float* __restrict__ Wc,
                                                  const float* __restrict__ bc,
                                                  float* __restrict__ out) {
  const int r = blockIdx.x;
  const int t = threadIdx.x;
  const int lane = t & 63, wv = t >> 6;
  __shared__ __align__(16) float srow[1536];
  __shared__ float red[4];
  __shared__ float pr[6][40];
  float h0 = hop[0], h1 = hop[1], h2 = hop[2];
  float hm = fmaxf(h0, fmaxf(h1, h2));
  float e0 = expf(h0 - hm), e1 = expf(h1 - hm), e2 = expf(h2 - hm);
  float minv = 1.f / (e0 + e1 + e2);
  float mask[3] = {e0 * minv, e1 * minv, e2 * minv};
  const float* Ts[3] = {T0, T1, T2};
#pragma unroll
  for (int s = 0; s < 3; s++) {
    float x0 = Ts[s][(size_t)r * DD + t];
    float x1 = Ts[s][(size_t)r * DD + t + 256];
    float ss = x0 * x0 + x1 * x1;
#pragma unroll
    for (int off = 32; off > 0; off >>= 1) ss += __shfl_xor(ss, off);
    if (lane == 0) red[wv] = ss;
    __syncthreads();
    float tot = red[0] + red[1] + red[2] + red[3];
    float nrm = fmaxf(sqrtf(tot), 1e-12f);
    float sc = mask[s] / nrm;
    srow[s * DD + t] = fmaxf(x0 * sc, 0.f);
    srow[s * DD + t + 256] = fmaxf(x1 * sc, 0.f);
    __syncthreads();
  }
  float part = 0.f;
  const int col = t % 40, seg = t / 40;
  if (seg < 6) {
    const float* w = Wc + col;
#pragma unroll 4
    for (int k = seg * 256; k < seg * 256 + 256; k++)
      part = fmaf(srow[k], w[(size_t)k * 40], part);
    pr[seg][col] = part;
  }
  __syncthreads();
  if (t < 64) {
    float lg = -INFINITY;
    if (t < 40) {
      lg = bc[t];
#pragma unroll
      for (int s6 = 0; s6 < 6; s6++) lg += pr[s6][t];
    }
    float mx = lg;
#pragma unroll
    for (int off = 32; off > 0; off >>= 1) mx = fmaxf(mx, __shfl_xor(mx, off));
    float ex = (t < 40) ? expf(lg - mx) : 0.f;
    float sm = ex;
#pragma unroll
    for (int off = 32; off > 0; off >>= 1) sm += __shfl_xor(sm, off);
    float ls = logf(sm);
    if (t < 40) out[(size_t)r * 40 + t] = lg - mx - ls;
  }
}

extern "C" void kernel_launch(void* const* d_in, const int* in_sizes, int n_in,
                              void* d_out, int out_size, void* d_ws, size_t ws_size,
                              hipStream_t stream) {
  (void)in_sizes; (void)n_in; (void)out_size; (void)ws_size;
  const float* x    = (const float*)d_in[0];
  const float* adjA = (const float*)d_in[1];
  const float* adj1 = (const float*)d_in[2];
  const float* adj2 = (const float*)d_in[3];
  const float* hop  = (const float*)d_in[4];
  const float* Wfc0 = (const float*)d_in[5];  const float* bfc0 = (const float*)d_in[6];
  const float* Wfc1 = (const float*)d_in[7];  const float* bfc1 = (const float*)d_in[8];
  const float* Wfc2 = (const float*)d_in[9];  const float* bfc2 = (const float*)d_in[10];
  const float* Wq0  = (const float*)d_in[11]; const float* bq0  = (const float*)d_in[12];
  const float* Wk0  = (const float*)d_in[13]; const float* bk0  = (const float*)d_in[14];
  const float* Wq1  = (const float*)d_in[15]; const float* bq1  = (const float*)d_in[16];
  const float* Wk1  = (const float*)d_in[17]; const float* bk1  = (const float*)d_in[18];
  const float* Wc   = (const float*)d_in[19]; const float* bc   = (const float*)d_in[20];

  float* ws = (float*)d_ws;
  const size_t MD = (size_t)NN * DD;
  float* TMP0 = ws + 0 * MD;
  float* TMP1 = ws + 1 * MD;
  float* TMP2 = ws + 2 * MD;
  float* TATT = ws + 3 * MD;
  float* U    = ws + 4 * MD;
  float* QB   = ws + 5 * MD;
  float* KB   = ws + 6 * MD;
  float* OUT1 = ws + 7 * MD;
  float* OUT2 = TATT;   // safe reuse: TATT is dead by the time OUT2 is written
  float* ATTV = ws + 8 * MD;
  int* ELLA = (int*)(ws + 8 * MD + (size_t)NN * ELL);
  int* ELL1 = ELLA + (size_t)NN * ELL;
  int* ELL2 = ELL1 + (size_t)NN * ELL;
  int* CNTA = ELL2 + (size_t)NN * ELL;
  int* CNT1 = CNTA + NN;
  int* CNT2 = CNT1 + NN;

  float* outLog = (float*)d_out;
  float* outAtt = outLog + (size_t)NN * 40;

  hipMemsetAsync(outAtt, 0, (size_t)NN * NN * sizeof(float), stream);

  k_build_ell<<<NN / 4, 256, 0, stream>>>(adjA, ELLA, CNTA);
  k_build_ell<<<NN / 4, 256, 0, stream>>>(adj1, ELL1, CNT1);
  k_build_ell<<<NN / 4, 256, 0, stream>>>(adj2, ELL2, CNT2);

  // tmp_i = x @ W_fc_i + b_fc_i, all three batched
  GemmP p1{x, Wfc0, Wfc1, Wfc2, bfc0, bfc1, bfc2, TMP0, TMP1, TMP2, nullptr};
  k_gemm<<<dim3(32, 12), 256, 0, stream>>>(p1);

  // ---------- layer 1 (adj1, Wq0/Wk0) ----------
  k_spmm<<<NN, 256, 0, stream>>>(ELLA, CNTA, nullptr, TMP1, TATT);   // t_att
  k_spmm<<<NN, 256, 0, stream>>>(ELLA, CNTA, nullptr, TATT, U);      // U = A*t_att
  GemmP p2{U, Wq0, Wk0, nullptr, bq0, bk0, nullptr, QB, KB, nullptr, CNTA};
  k_gemm<<<dim3(32, 8), 256, 0, stream>>>(p2);                       // Q,K
  k_sddmm_softmax<<<NN, 256, 0, stream>>>(ELL1, CNT1, QB, KB, ATTV, nullptr);
  k_spmm<<<NN, 256, 0, stream>>>(ELL1, CNT1, ATTV, TMP1, OUT1);      // att @ tmp

  // ---------- layer 2 (adj2, Wq1/Wk1) ----------
  k_spmm<<<NN, 256, 0, stream>>>(ELLA, CNTA, nullptr, TMP2, TATT);
  k_spmm<<<NN, 256, 0, stream>>>(ELLA, CNTA, nullptr, TATT, U);
  GemmP p3{U, Wq1, Wk1, nullptr, bq1, bk1, nullptr, QB, KB, nullptr, CNTA};
  k_gemm<<<dim3(32, 8), 256, 0, stream>>>(p3);
  k_sddmm_softmax<<<NN, 256, 0, stream>>>(ELL2, CNT2, QB, KB, ATTV, outAtt);
  k_spmm<<<NN, 256, 0, stream>>>(ELL2, CNT2, ATTV, TMP2, OUT2);

  k_norm_cls<<<NN, 256, 0, stream>>>(TMP0, OUT1, OUT2, hop, Wc, bc, outLog);
}